// Round 7
// baseline (181.187 us; speedup 1.0000x reference)
//
#include <hip/hip_runtime.h>

typedef __bf16 bf16;
typedef __bf16 bf16x8 __attribute__((ext_vector_type(8)));
typedef float  f32x4  __attribute__((ext_vector_type(4)));

#define MFMA(a, b, c) __builtin_amdgcn_mfma_f32_16x16x32_bf16((a), (b), (c), 0, 0, 0)

static constexpr int B_   = 2;
static constexpr int T_   = 2048;
static constexpr int D_   = 1024;
static constexpr int NH_  = 16;
static constexpr int HD_  = 64;
static constexpr int WIN_ = 256;
static constexpr int M_   = B_ * T_;          // 4096
static constexpr int NQKV = D_ + 2 * HD_;     // 1152

// async global->LDS, 16B per lane; global addr per-lane, LDS dst wave-uniform
// base + lane*16 [m97/m104-verified]
__device__ __forceinline__ void gld_lds16(const bf16* g, bf16* l) {
  __builtin_amdgcn_global_load_lds(
      (const __attribute__((address_space(1))) void*)g,
      (__attribute__((address_space(3))) void*)l, 16, 0, 0);
}

// ---------------------------------------------------------------------------
// Fused fp32->bf16 conversion of all 6 inputs. Wq/Wk/Wv -> Wqkv[1152][1024].
// ---------------------------------------------------------------------------
__global__ __launch_bounds__(256) void conv_all(
    const float* __restrict__ x,  const float* __restrict__ wq,
    const float* __restrict__ wk, const float* __restrict__ wv,
    const float* __restrict__ wf, const float* __restrict__ bv,
    bf16* __restrict__ xc, bf16* __restrict__ wqkv,
    bf16* __restrict__ wfc, bf16* __restrict__ bfc) {
  const long i = (long)(blockIdx.x * 256 + threadIdx.x) * 4;
  const float* src; bf16* dst; long off;
  if      (i < 4194304L) { src = x;  dst = xc;              off = 0; }
  else if (i < 5242880L) { src = wq; dst = wqkv;            off = 4194304L; }
  else if (i < 5308416L) { src = wk; dst = wqkv + 1048576L; off = 5242880L; }
  else if (i < 5373952L) { src = wv; dst = wqkv + 1114112L; off = 5308416L; }
  else if (i < 6422528L) { src = wf; dst = wfc;             off = 5373952L; }
  else if (i < 6423552L) { src = bv; dst = bfc;             off = 6422528L; }
  else return;
  const long j = i - off;
  const float4 v = *(const float4*)(src + j);
  bf16 o[4] = {(bf16)v.x, (bf16)v.y, (bf16)v.z, (bf16)v.w};
  *(uint2*)(dst + j) = *(const uint2*)o;
}

// ---------------------------------------------------------------------------
// GEMM, tile M=64 x N=128, BK=128, 256 thr = 4 waves; wave = 32x64 (2x4 MFMA,
// 4 kk-steps -> 32 MFMA per barrier pair; 8 K-iters instead of 16 halves the
// vmcnt(0)+barrier drains, the m97-structural stall). LDS 48 KB -> 3 blk/CU
// (grid 2.25/CU is the binding limit, so no occupancy loss vs BK=64).
// C[M,N] = A[M,K] @ B[N,K]^T.
// EPI=1: QKV split (q SCALED by 0.125 / k / vT transposed). EPI=2: fp32+bias.
// ---------------------------------------------------------------------------
template <int EPI>
__global__ __launch_bounds__(256) void gemm64x128(
    const bf16* __restrict__ A, const bf16* __restrict__ Bw,
    void* __restrict__ Cout, const bf16* __restrict__ bias,
    bf16* __restrict__ kb, bf16* __restrict__ vT, int N, int K) {
  __shared__ __align__(16) bf16 As[64 * 128];    // 16 KB
  __shared__ __align__(16) bf16 Bs[128 * 128];   // 32 KB

  const int tid  = threadIdx.x;
  const int w    = tid >> 6;
  const int lane = tid & 63;
  const int quad = lane >> 4;
  const int l16  = lane & 15;
  const int wm   = w & 1;   // row half (32 rows)
  const int wn   = w >> 1;  // col half (64 cols)
  const int m0   = blockIdx.x * 64;
  const int n0   = blockIdx.y * 128;
  const int lrow = lane >> 4;         // 0..3  (4 rows per 16B-inst @128 cols)
  const int lcol = (lane & 15) * 8;   // 0..120

  f32x4 acc[2][4] = {};

  for (int k0 = 0; k0 < K; k0 += 128) {
    __syncthreads();
    // 48 gld_lds16 insts: 16 for As (64 rows), 32 for Bs (128 rows); 12/wave
#pragma unroll
    for (int t = 0; t < 12; ++t) {
      const int inst = w * 12 + t;  // wave-uniform
      if (inst < 16) {
        gld_lds16(&A[(size_t)(m0 + inst * 4 + lrow) * K + k0 + lcol],
                  &As[inst * 512]);
      } else {
        const int bi = inst - 16;
        gld_lds16(&Bw[(size_t)(n0 + bi * 4 + lrow) * K + k0 + lcol],
                  &Bs[bi * 512]);
      }
    }
    __syncthreads();
#pragma unroll
    for (int kk = 0; kk < 128; kk += 32) {
      bf16x8 a[2], b[4];
#pragma unroll
      for (int i = 0; i < 2; ++i)
        a[i] = *(const bf16x8*)&As[(wm * 32 + i * 16 + l16) * 128 + kk + quad * 8];
#pragma unroll
      for (int j = 0; j < 4; ++j)
        b[j] = *(const bf16x8*)&Bs[(wn * 64 + j * 16 + l16) * 128 + kk + quad * 8];
#pragma unroll
      for (int i = 0; i < 2; ++i)
#pragma unroll
        for (int j = 0; j < 4; ++j) acc[i][j] = MFMA(a[i], b[j], acc[i][j]);
    }
  }

  // epilogue: C/D layout col=l16, row=quad*4+r (m89-verified)
#pragma unroll
  for (int i = 0; i < 2; ++i) {
#pragma unroll
    for (int j = 0; j < 4; ++j) {
      const int col     = n0 + wn * 64 + j * 16 + l16;
      const int rowbase = m0 + wm * 32 + i * 16 + quad * 4;
      if (EPI == 1) {
        if (col < D_) {
          bf16* qb = (bf16*)Cout;
#pragma unroll
          for (int r = 0; r < 4; ++r)  // fold softmax scale 1/sqrt(64) into q
            qb[(size_t)(rowbase + r) * D_ + col] = (bf16)(acc[i][j][r] * 0.125f);
        } else if (col < D_ + HD_) {
#pragma unroll
          for (int r = 0; r < 4; ++r)
            kb[(size_t)(rowbase + r) * HD_ + (col - D_)] = (bf16)acc[i][j][r];
        } else {
          bf16 o[4] = {(bf16)acc[i][j][0], (bf16)acc[i][j][1],
                       (bf16)acc[i][j][2], (bf16)acc[i][j][3]};
          *(uint2*)&vT[(size_t)(col - D_ - HD_) * M_ + rowbase] = *(const uint2*)o;
        }
      } else {
        float* outp = (float*)Cout;
        const float bvv = (float)bias[col];
#pragma unroll
        for (int r = 0; r < 4; ++r)
          outp[(size_t)(rowbase + r) * D_ + col] = acc[i][j][r] + bvv;
      }
    }
  }
}

// ---------------------------------------------------------------------------
// Windowed attention (MQA), Q-tile = 128. q arrives pre-scaled by 1/sqrt(64).
// Wave-uniform mask hoisting: for wave w and s-tile offset o = st - t0, the
// wave's 32 rows need masking only if o < w*32-225 or o > w*32+193 (~3 of 10
// tiles) -> ~70% of softmax elements skip cmp/cndmask (r4: VALU-bound).
// V pre-transposed (vT[h][m]); un-normalized softmax (NaN-free); Ps stride 72.
// In-place safe: block exclusively owns its (t-tile, head) q/o slice.
// ---------------------------------------------------------------------------
__global__ __launch_bounds__(256) void attn_win128(
    const bf16* __restrict__ q, const bf16* __restrict__ k,
    const bf16* __restrict__ vT, bf16* __restrict__ o) {
  __shared__ __align__(16) bf16 Qs[128 * 64];   // 16 KB
  __shared__ __align__(16) bf16 Ks[64 * 64];    //  8 KB
  __shared__ __align__(16) bf16 Vt[64 * 64];    //  8 KB [h][s]
  __shared__ __align__(16) bf16 Ps[128 * 72];   // 18 KB padded

  const int tid  = threadIdx.x;
  const int w    = tid >> 6;
  const int lane = tid & 63;
  const int quad = lane >> 4;
  const int l16  = lane & 15;
  const int lrow = lane >> 3;        // 0..7
  const int lcol = (lane & 7) * 8;   // 0..56

  const int t0 = blockIdx.x * 128;
  const int n  = blockIdx.y;
  const int b  = blockIdx.z;

  // stage Q tile (128 rows x 64): 16 insts, 4 per wave
#pragma unroll
  for (int t = 0; t < 4; ++t) {
    const int inst = w * 4 + t;
    gld_lds16(&q[((size_t)(b * T_ + t0 + inst * 8 + lrow)) * D_ + n * HD_ + lcol],
              &Qs[inst * 512]);
  }

  f32x4 o_acc[2][4] = {};
  float l_r[2][4] = {};

  for (int st = t0 - WIN_; st <= t0 + WIN_ + 64; st += 64) {
    if (st < 0 || st >= T_) continue;  // aligned tiles, block-uniform

    __syncthreads();  // prior iteration's LDS reads complete
#pragma unroll
    for (int t = 0; t < 2; ++t) {
      const int inst = w * 2 + t;
      gld_lds16(&k[((size_t)(b * T_ + st + inst * 8 + lrow)) * HD_ + lcol],
                &Ks[inst * 512]);
      gld_lds16(&vT[(size_t)(inst * 8 + lrow) * M_ + b * T_ + st + lcol],
                &Vt[inst * 512]);
    }
    __syncthreads();

    // S = Q K^T : wave w's 32 rows (2 row-groups of 16) x 64 cols
    f32x4 sacc[2][4] = {};
#pragma unroll
    for (int kk = 0; kk < 64; kk += 32) {
      bf16x8 aq[2];
#pragma unroll
      for (int rg = 0; rg < 2; ++rg)
        aq[rg] = *(const bf16x8*)&Qs[(w * 32 + rg * 16 + l16) * 64 + kk + quad * 8];
#pragma unroll
      for (int nt = 0; nt < 4; ++nt) {
        bf16x8 bk = *(const bf16x8*)&Ks[(nt * 16 + l16) * 64 + kk + quad * 8];
#pragma unroll
        for (int rg = 0; rg < 2; ++rg) sacc[rg][nt] = MFMA(aq[rg], bk, sacc[rg][nt]);
      }
    }

    // softmax numerators; wave-uniform branch on whether masking is needed
    const int off_t = st - t0;
    const bool need_mask =
        (off_t < w * 32 - (WIN_ - 31)) || (off_t > w * 32 + (WIN_ - 63));
    if (!need_mask) {
#pragma unroll
      for (int rg = 0; rg < 2; ++rg)
#pragma unroll
        for (int r = 0; r < 4; ++r) {
#pragma unroll
          for (int nt = 0; nt < 4; ++nt) {
            const float p = __expf(fminf(sacc[rg][nt][r], 30.0f));
            l_r[rg][r] += p;
            Ps[(w * 32 + rg * 16 + quad * 4 + r) * 72 + nt * 16 + l16] = (bf16)p;
          }
        }
    } else {
#pragma unroll
      for (int rg = 0; rg < 2; ++rg)
#pragma unroll
        for (int r = 0; r < 4; ++r) {
          const int t = t0 + w * 32 + rg * 16 + quad * 4 + r;
#pragma unroll
          for (int nt = 0; nt < 4; ++nt) {
            const int s = st + nt * 16 + l16;
            const int d = t - s;
            float p = (d > WIN_ || d < -WIN_)
                          ? 0.0f
                          : __expf(fminf(sacc[rg][nt][r], 30.0f));
            l_r[rg][r] += p;
            Ps[(w * 32 + rg * 16 + quad * 4 + r) * 72 + nt * 16 + l16] = (bf16)p;
          }
        }
    }
    __syncthreads();

    // O += P V
#pragma unroll
    for (int kk = 0; kk < 64; kk += 32) {
      bf16x8 ap[2];
#pragma unroll
      for (int rg = 0; rg < 2; ++rg)
        ap[rg] = *(const bf16x8*)&Ps[(w * 32 + rg * 16 + l16) * 72 + kk + quad * 8];
#pragma unroll
      for (int nt = 0; nt < 4; ++nt) {
        bf16x8 bv = *(const bf16x8*)&Vt[(nt * 16 + l16) * 64 + kk + quad * 8];
#pragma unroll
        for (int rg = 0; rg < 2; ++rg)
          o_acc[rg][nt] = MFMA(ap[rg], bv, o_acc[rg][nt]);
      }
    }
  }

#pragma unroll
  for (int rg = 0; rg < 2; ++rg)
#pragma unroll
    for (int r = 0; r < 4; ++r)
#pragma unroll
      for (int off = 1; off < 16; off <<= 1)
        l_r[rg][r] += __shfl_xor(l_r[rg][r], off);

#pragma unroll
  for (int rg = 0; rg < 2; ++rg) {
#pragma unroll
    for (int nt = 0; nt < 4; ++nt) {
#pragma unroll
      for (int r = 0; r < 4; ++r) {
        const int t = t0 + w * 32 + rg * 16 + quad * 4 + r;
        const int h = nt * 16 + l16;
        o[((size_t)(b * T_ + t)) * D_ + n * HD_ + h] =
            (bf16)(o_acc[rg][nt][r] / (l_r[rg][r] + 1e-30f));
      }
    }
  }
}

// ---------------------------------------------------------------------------
extern "C" void kernel_launch(void* const* d_in, const int* in_sizes, int n_in,
                              void* d_out, int out_size, void* d_ws, size_t ws_size,
                              hipStream_t stream) {
  float* out = (float*)d_out;  // reference output dtype is float32

  bf16* xc   = (bf16*)d_ws;                   // 4096 x 1024
  bf16* wqkv = xc   + (size_t)M_ * D_;        // 1152 x 1024
  bf16* wfc  = wqkv + (size_t)NQKV * D_;      // 1024 x 1024
  bf16* bfc  = wfc  + (size_t)D_ * D_;        // 1024
  bf16* qb   = bfc  + D_;                     // 4096 x 1024 (attn out in-place)
  bf16* kb   = qb   + (size_t)M_ * D_;        // 4096 x 64
  bf16* vT   = kb   + (size_t)M_ * HD_;       // 64 x 4096 (transposed)

  dim3 blk(256);
  conv_all<<<dim3((6423552 / 4 + 255) / 256), blk, 0, stream>>>(
      (const float*)d_in[0], (const float*)d_in[1], (const float*)d_in[2],
      (const float*)d_in[3], (const float*)d_in[4], (const float*)d_in[5],
      xc, wqkv, wfc, bfc);

  gemm64x128<1><<<dim3(M_ / 64, NQKV / 128), blk, 0, stream>>>(
      xc, wqkv, (void*)qb, nullptr, kb, vT, NQKV, D_);

  attn_win128<<<dim3(T_ / 128, NH_, B_), blk, 0, stream>>>(qb, kb, vT, qb);

  gemm64x128<2><<<dim3(M_ / 64, D_ / 128), blk, 0, stream>>>(
      qb, wfc, (void*)out, bfc, nullptr, nullptr, D_, D_);
}

// Round 8
// 158.714 us; speedup vs baseline: 1.1416x; 1.1416x over previous
//
#include <hip/hip_runtime.h>

typedef __bf16 bf16;
typedef __bf16 bf16x8 __attribute__((ext_vector_type(8)));
typedef float  f32x4  __attribute__((ext_vector_type(4)));

#define MFMA(a, b, c) __builtin_amdgcn_mfma_f32_16x16x32_bf16((a), (b), (c), 0, 0, 0)

static constexpr int B_   = 2;
static constexpr int T_   = 2048;
static constexpr int D_   = 1024;
static constexpr int NH_  = 16;
static constexpr int HD_  = 64;
static constexpr int WIN_ = 256;
static constexpr int M_   = B_ * T_;          // 4096
static constexpr int NQKV = D_ + 2 * HD_;     // 1152

// async global->LDS, 16B per lane; global addr per-lane, LDS dst wave-uniform
// base + lane*16 [m97/m104-verified]
__device__ __forceinline__ void gld_lds16(const bf16* g, bf16* l) {
  __builtin_amdgcn_global_load_lds(
      (const __attribute__((address_space(1))) void*)g,
      (__attribute__((address_space(3))) void*)l, 16, 0, 0);
}

// ---------------------------------------------------------------------------
// Fused fp32->bf16 conversion of all 6 inputs. Wq/Wk/Wv -> Wqkv[1152][1024].
// ---------------------------------------------------------------------------
__global__ __launch_bounds__(256) void conv_all(
    const float* __restrict__ x,  const float* __restrict__ wq,
    const float* __restrict__ wk, const float* __restrict__ wv,
    const float* __restrict__ wf, const float* __restrict__ bv,
    bf16* __restrict__ xc, bf16* __restrict__ wqkv,
    bf16* __restrict__ wfc, bf16* __restrict__ bfc) {
  const long i = (long)(blockIdx.x * 256 + threadIdx.x) * 4;
  const float* src; bf16* dst; long off;
  if      (i < 4194304L) { src = x;  dst = xc;              off = 0; }
  else if (i < 5242880L) { src = wq; dst = wqkv;            off = 4194304L; }
  else if (i < 5308416L) { src = wk; dst = wqkv + 1048576L; off = 5242880L; }
  else if (i < 5373952L) { src = wv; dst = wqkv + 1114112L; off = 5308416L; }
  else if (i < 6422528L) { src = wf; dst = wfc;             off = 5373952L; }
  else if (i < 6423552L) { src = bv; dst = bfc;             off = 6422528L; }
  else return;
  const long j = i - off;
  const float4 v = *(const float4*)(src + j);
  bf16 o[4] = {(bf16)v.x, (bf16)v.y, (bf16)v.z, (bf16)v.w};
  *(uint2*)(dst + j) = *(const uint2*)o;
}

// ---------------------------------------------------------------------------
// GEMM, tile M=64 x N=128, BK=64 (r6-benched structure; BK=128 regressed per
// r7 + m132 precedent: one big vmcnt(0) drain overlaps with nothing).
// 256 thr = 4 waves; wave = 32x64 (2x4 MFMA). Grids 576/512 blocks (2.25/CU).
// C[M,N] = A[M,K] @ B[N,K]^T.
// EPI=1: QKV split (q SCALED by 0.125 / k / vT transposed). EPI=2: fp32+bias.
// ---------------------------------------------------------------------------
template <int EPI>
__global__ __launch_bounds__(256) void gemm64x128(
    const bf16* __restrict__ A, const bf16* __restrict__ Bw,
    void* __restrict__ Cout, const bf16* __restrict__ bias,
    bf16* __restrict__ kb, bf16* __restrict__ vT, int N, int K) {
  __shared__ __align__(16) bf16 As[64 * 64];    //  8 KB
  __shared__ __align__(16) bf16 Bs[128 * 64];   // 16 KB

  const int tid  = threadIdx.x;
  const int w    = tid >> 6;
  const int lane = tid & 63;
  const int quad = lane >> 4;
  const int l16  = lane & 15;
  const int wm   = w & 1;   // row half (32 rows)
  const int wn   = w >> 1;  // col half (64 cols)
  const int m0   = blockIdx.x * 64;
  const int n0   = blockIdx.y * 128;
  const int lrow = lane >> 3;        // 0..7
  const int lcol = (lane & 7) * 8;   // 0..56

  f32x4 acc[2][4] = {};

  for (int k0 = 0; k0 < K; k0 += 64) {
    __syncthreads();
    // 24 gld_lds16 insts: 8 for As (64 rows), 16 for Bs (128 rows); 6/wave
#pragma unroll
    for (int t = 0; t < 6; ++t) {
      const int inst = w * 6 + t;  // wave-uniform
      if (inst < 8) {
        gld_lds16(&A[(size_t)(m0 + inst * 8 + lrow) * K + k0 + lcol],
                  &As[inst * 512]);
      } else {
        const int bi = inst - 8;
        gld_lds16(&Bw[(size_t)(n0 + bi * 8 + lrow) * K + k0 + lcol],
                  &Bs[bi * 512]);
      }
    }
    __syncthreads();
#pragma unroll
    for (int kk = 0; kk < 64; kk += 32) {
      bf16x8 a[2], b[4];
#pragma unroll
      for (int i = 0; i < 2; ++i)
        a[i] = *(const bf16x8*)&As[(wm * 32 + i * 16 + l16) * 64 + kk + quad * 8];
#pragma unroll
      for (int j = 0; j < 4; ++j)
        b[j] = *(const bf16x8*)&Bs[(wn * 64 + j * 16 + l16) * 64 + kk + quad * 8];
#pragma unroll
      for (int i = 0; i < 2; ++i)
#pragma unroll
        for (int j = 0; j < 4; ++j) acc[i][j] = MFMA(a[i], b[j], acc[i][j]);
    }
  }

  // epilogue: C/D layout col=l16, row=quad*4+r (m89-verified)
#pragma unroll
  for (int i = 0; i < 2; ++i) {
#pragma unroll
    for (int j = 0; j < 4; ++j) {
      const int col     = n0 + wn * 64 + j * 16 + l16;
      const int rowbase = m0 + wm * 32 + i * 16 + quad * 4;
      if (EPI == 1) {
        if (col < D_) {
          bf16* qb = (bf16*)Cout;
#pragma unroll
          for (int r = 0; r < 4; ++r)  // fold softmax scale 1/sqrt(64) into q
            qb[(size_t)(rowbase + r) * D_ + col] = (bf16)(acc[i][j][r] * 0.125f);
        } else if (col < D_ + HD_) {
#pragma unroll
          for (int r = 0; r < 4; ++r)
            kb[(size_t)(rowbase + r) * HD_ + (col - D_)] = (bf16)acc[i][j][r];
        } else {
          bf16 o[4] = {(bf16)acc[i][j][0], (bf16)acc[i][j][1],
                       (bf16)acc[i][j][2], (bf16)acc[i][j][3]};
          *(uint2*)&vT[(size_t)(col - D_ - HD_) * M_ + rowbase] = *(const uint2*)o;
        }
      } else {
        float* outp = (float*)Cout;
        const float bvv = (float)bias[col];
#pragma unroll
        for (int r = 0; r < 4; ++r)
          outp[(size_t)(rowbase + r) * D_ + col] = acc[i][j][r] + bvv;
      }
    }
  }
}

// ---------------------------------------------------------------------------
// Windowed attention (MQA), Q-tile = 128, q pre-scaled by 1/sqrt(64).
// DOUBLE-BUFFERED K/V: tile i+1's global_load_lds is issued right after the
// top barrier of iter i, so its flight time overlaps QK+softmax (it drains at
// the mid-iter Ps barrier). Hazard-safe: top barrier of iter i guarantees all
// PV reads of buf^1 (iter i-1) completed before any wave's prefetch writes.
// LDS 66 KB -> 2 blocks/CU = exactly the grid limit (512 blocks), no loss.
// Wave-uniform mask hoisting (~3 of 10 tiles take the masked path).
// Un-normalized softmax (NaN-free); Ps stride 72; in-place q/o safe.
// ---------------------------------------------------------------------------
__global__ __launch_bounds__(256) void attn_win128(
    const bf16* __restrict__ q, const bf16* __restrict__ k,
    const bf16* __restrict__ vT, bf16* __restrict__ o) {
  __shared__ __align__(16) bf16 Qs[128 * 64];     // 16 KB
  __shared__ __align__(16) bf16 Ks[2][64 * 64];   // 16 KB
  __shared__ __align__(16) bf16 Vt[2][64 * 64];   // 16 KB [h][s]
  __shared__ __align__(16) bf16 Ps[128 * 72];     // 18 KB padded

  const int tid  = threadIdx.x;
  const int w    = tid >> 6;
  const int lane = tid & 63;
  const int quad = lane >> 4;
  const int l16  = lane & 15;
  const int lrow = lane >> 3;        // 0..7
  const int lcol = (lane & 7) * 8;   // 0..56

  const int t0 = blockIdx.x * 128;
  const int n  = blockIdx.y;
  const int b  = blockIdx.z;

  // stage Q tile (128 rows x 64): 16 insts, 4 per wave
#pragma unroll
  for (int t = 0; t < 4; ++t) {
    const int inst = w * 4 + t;
    gld_lds16(&q[((size_t)(b * T_ + t0 + inst * 8 + lrow)) * D_ + n * HD_ + lcol],
              &Qs[inst * 512]);
  }

  auto stageKV = [&](int st, int pb) {
#pragma unroll
    for (int t = 0; t < 2; ++t) {
      const int inst = w * 2 + t;
      gld_lds16(&k[((size_t)(b * T_ + st + inst * 8 + lrow)) * HD_ + lcol],
                &Ks[pb][inst * 512]);
      gld_lds16(&vT[(size_t)(inst * 8 + lrow) * M_ + b * T_ + st + lcol],
                &Vt[pb][inst * 512]);
    }
  };

  const int st_lo = (t0 - WIN_ > 0) ? t0 - WIN_ : 0;
  const int st_hi = (t0 + WIN_ + 64 < T_ - 64) ? t0 + WIN_ + 64 : T_ - 64;

  stageKV(st_lo, 0);
  int pb = 0;

  f32x4 o_acc[2][4] = {};
  float l_r[2][4] = {};

  for (int st = st_lo; st <= st_hi; st += 64) {
    __syncthreads();  // drains vmcnt: buf[pb] (and Qs) ready; prior PV done
    if (st + 64 <= st_hi) stageKV(st + 64, pb ^ 1);  // overlapped prefetch

    // S = Q K^T : wave w's 32 rows (2 row-groups of 16) x 64 cols
    f32x4 sacc[2][4] = {};
#pragma unroll
    for (int kk = 0; kk < 64; kk += 32) {
      bf16x8 aq[2];
#pragma unroll
      for (int rg = 0; rg < 2; ++rg)
        aq[rg] = *(const bf16x8*)&Qs[(w * 32 + rg * 16 + l16) * 64 + kk + quad * 8];
#pragma unroll
      for (int nt = 0; nt < 4; ++nt) {
        bf16x8 bk = *(const bf16x8*)&Ks[pb][(nt * 16 + l16) * 64 + kk + quad * 8];
#pragma unroll
        for (int rg = 0; rg < 2; ++rg) sacc[rg][nt] = MFMA(aq[rg], bk, sacc[rg][nt]);
      }
    }

    // softmax numerators; wave-uniform branch on whether masking is needed
    const int off_t = st - t0;
    const bool need_mask =
        (off_t < w * 32 - (WIN_ - 31)) || (off_t > w * 32 + (WIN_ - 63));
    if (!need_mask) {
#pragma unroll
      for (int rg = 0; rg < 2; ++rg)
#pragma unroll
        for (int r = 0; r < 4; ++r) {
#pragma unroll
          for (int nt = 0; nt < 4; ++nt) {
            const float p = __expf(fminf(sacc[rg][nt][r], 30.0f));
            l_r[rg][r] += p;
            Ps[(w * 32 + rg * 16 + quad * 4 + r) * 72 + nt * 16 + l16] = (bf16)p;
          }
        }
    } else {
#pragma unroll
      for (int rg = 0; rg < 2; ++rg)
#pragma unroll
        for (int r = 0; r < 4; ++r) {
          const int t = t0 + w * 32 + rg * 16 + quad * 4 + r;
#pragma unroll
          for (int nt = 0; nt < 4; ++nt) {
            const int s = st + nt * 16 + l16;
            const int d = t - s;
            float p = (d > WIN_ || d < -WIN_)
                          ? 0.0f
                          : __expf(fminf(sacc[rg][nt][r], 30.0f));
            l_r[rg][r] += p;
            Ps[(w * 32 + rg * 16 + quad * 4 + r) * 72 + nt * 16 + l16] = (bf16)p;
          }
        }
    }
    __syncthreads();  // Ps visible (prefetch drains here, overlapped)

    // O += P V
#pragma unroll
    for (int kk = 0; kk < 64; kk += 32) {
      bf16x8 ap[2];
#pragma unroll
      for (int rg = 0; rg < 2; ++rg)
        ap[rg] = *(const bf16x8*)&Ps[(w * 32 + rg * 16 + l16) * 72 + kk + quad * 8];
#pragma unroll
      for (int nt = 0; nt < 4; ++nt) {
        bf16x8 bv = *(const bf16x8*)&Vt[pb][(nt * 16 + l16) * 64 + kk + quad * 8];
#pragma unroll
        for (int rg = 0; rg < 2; ++rg)
          o_acc[rg][nt] = MFMA(ap[rg], bv, o_acc[rg][nt]);
      }
    }
    pb ^= 1;
  }

#pragma unroll
  for (int rg = 0; rg < 2; ++rg)
#pragma unroll
    for (int r = 0; r < 4; ++r)
#pragma unroll
      for (int off = 1; off < 16; off <<= 1)
        l_r[rg][r] += __shfl_xor(l_r[rg][r], off);

#pragma unroll
  for (int rg = 0; rg < 2; ++rg) {
#pragma unroll
    for (int nt = 0; nt < 4; ++nt) {
#pragma unroll
      for (int r = 0; r < 4; ++r) {
        const int t = t0 + w * 32 + rg * 16 + quad * 4 + r;
        const int h = nt * 16 + l16;
        o[((size_t)(b * T_ + t)) * D_ + n * HD_ + h] =
            (bf16)(o_acc[rg][nt][r] / (l_r[rg][r] + 1e-30f));
      }
    }
  }
}

// ---------------------------------------------------------------------------
extern "C" void kernel_launch(void* const* d_in, const int* in_sizes, int n_in,
                              void* d_out, int out_size, void* d_ws, size_t ws_size,
                              hipStream_t stream) {
  float* out = (float*)d_out;  // reference output dtype is float32

  bf16* xc   = (bf16*)d_ws;                   // 4096 x 1024
  bf16* wqkv = xc   + (size_t)M_ * D_;        // 1152 x 1024
  bf16* wfc  = wqkv + (size_t)NQKV * D_;      // 1024 x 1024
  bf16* bfc  = wfc  + (size_t)D_ * D_;        // 1024
  bf16* qb   = bfc  + D_;                     // 4096 x 1024 (attn out in-place)
  bf16* kb   = qb   + (size_t)M_ * D_;        // 4096 x 64
  bf16* vT   = kb   + (size_t)M_ * HD_;       // 64 x 4096 (transposed)

  dim3 blk(256);
  conv_all<<<dim3((6423552 / 4 + 255) / 256), blk, 0, stream>>>(
      (const float*)d_in[0], (const float*)d_in[1], (const float*)d_in[2],
      (const float*)d_in[3], (const float*)d_in[4], (const float*)d_in[5],
      xc, wqkv, wfc, bfc);

  gemm64x128<1><<<dim3(M_ / 64, NQKV / 128), blk, 0, stream>>>(
      xc, wqkv, (void*)qb, nullptr, kb, vT, NQKV, D_);

  attn_win128<<<dim3(T_ / 128, NH_, B_), blk, 0, stream>>>(qb, kb, vT, qb);

  gemm64x128<2><<<dim3(M_ / 64, D_ / 128), blk, 0, stream>>>(
      qb, wfc, (void*)out, bfc, nullptr, nullptr, D_, D_);
}

// Round 9
// 156.483 us; speedup vs baseline: 1.1579x; 1.0143x over previous
//
#include <hip/hip_runtime.h>

typedef __bf16 bf16;
typedef __bf16 bf16x8 __attribute__((ext_vector_type(8)));
typedef float  f32x4  __attribute__((ext_vector_type(4)));

#define MFMA(a, b, c) __builtin_amdgcn_mfma_f32_16x16x32_bf16((a), (b), (c), 0, 0, 0)

static constexpr int B_   = 2;
static constexpr int T_   = 2048;
static constexpr int D_   = 1024;
static constexpr int NH_  = 16;
static constexpr int HD_  = 64;
static constexpr int WIN_ = 256;
static constexpr int M_   = B_ * T_;          // 4096
static constexpr int NQKV = D_ + 2 * HD_;     // 1152

// async global->LDS, 16B per lane; global addr per-lane, LDS dst wave-uniform
// base + lane*16 [m97/m104-verified]
__device__ __forceinline__ void gld_lds16(const bf16* g, bf16* l) {
  __builtin_amdgcn_global_load_lds(
      (const __attribute__((address_space(1))) void*)g,
      (__attribute__((address_space(3))) void*)l, 16, 0, 0);
}

// ---------------------------------------------------------------------------
// Fused fp32->bf16 conversion of all 6 inputs. Wq/Wk/Wv -> Wqkv[1152][1024].
// ---------------------------------------------------------------------------
__global__ __launch_bounds__(256) void conv_all(
    const float* __restrict__ x,  const float* __restrict__ wq,
    const float* __restrict__ wk, const float* __restrict__ wv,
    const float* __restrict__ wf, const float* __restrict__ bv,
    bf16* __restrict__ xc, bf16* __restrict__ wqkv,
    bf16* __restrict__ wfc, bf16* __restrict__ bfc) {
  const long i = (long)(blockIdx.x * 256 + threadIdx.x) * 4;
  const float* src; bf16* dst; long off;
  if      (i < 4194304L) { src = x;  dst = xc;              off = 0; }
  else if (i < 5242880L) { src = wq; dst = wqkv;            off = 4194304L; }
  else if (i < 5308416L) { src = wk; dst = wqkv + 1048576L; off = 5242880L; }
  else if (i < 5373952L) { src = wv; dst = wqkv + 1114112L; off = 5308416L; }
  else if (i < 6422528L) { src = wf; dst = wfc;             off = 5373952L; }
  else if (i < 6423552L) { src = bv; dst = bfc;             off = 6422528L; }
  else return;
  const long j = i - off;
  const float4 v = *(const float4*)(src + j);
  bf16 o[4] = {(bf16)v.x, (bf16)v.y, (bf16)v.z, (bf16)v.w};
  *(uint2*)(dst + j) = *(const uint2*)o;
}

// ---------------------------------------------------------------------------
// GEMM, tile M=64 x N=128, BK=64 (r6/r8-benched structure; BK=128 regressed,
// r7 + m132 precedent). 256 thr = 4 waves; wave = 32x64 (2x4 MFMA).
// C[M,N] = A[M,K] @ B[N,K]^T.
// EPI=1: QKV split (q SCALED by 0.125 / k / vT transposed). EPI=2: fp32+bias.
// ---------------------------------------------------------------------------
template <int EPI>
__global__ __launch_bounds__(256) void gemm64x128(
    const bf16* __restrict__ A, const bf16* __restrict__ Bw,
    void* __restrict__ Cout, const bf16* __restrict__ bias,
    bf16* __restrict__ kb, bf16* __restrict__ vT, int N, int K) {
  __shared__ __align__(16) bf16 As[64 * 64];    //  8 KB
  __shared__ __align__(16) bf16 Bs[128 * 64];   // 16 KB

  const int tid  = threadIdx.x;
  const int w    = tid >> 6;
  const int lane = tid & 63;
  const int quad = lane >> 4;
  const int l16  = lane & 15;
  const int wm   = w & 1;   // row half (32 rows)
  const int wn   = w >> 1;  // col half (64 cols)
  const int m0   = blockIdx.x * 64;
  const int n0   = blockIdx.y * 128;
  const int lrow = lane >> 3;        // 0..7
  const int lcol = (lane & 7) * 8;   // 0..56

  f32x4 acc[2][4] = {};

  for (int k0 = 0; k0 < K; k0 += 64) {
    __syncthreads();
    // 24 gld_lds16 insts: 8 for As (64 rows), 16 for Bs (128 rows); 6/wave
#pragma unroll
    for (int t = 0; t < 6; ++t) {
      const int inst = w * 6 + t;  // wave-uniform
      if (inst < 8) {
        gld_lds16(&A[(size_t)(m0 + inst * 8 + lrow) * K + k0 + lcol],
                  &As[inst * 512]);
      } else {
        const int bi = inst - 8;
        gld_lds16(&Bw[(size_t)(n0 + bi * 8 + lrow) * K + k0 + lcol],
                  &Bs[bi * 512]);
      }
    }
    __syncthreads();
#pragma unroll
    for (int kk = 0; kk < 64; kk += 32) {
      bf16x8 a[2], b[4];
#pragma unroll
      for (int i = 0; i < 2; ++i)
        a[i] = *(const bf16x8*)&As[(wm * 32 + i * 16 + l16) * 64 + kk + quad * 8];
#pragma unroll
      for (int j = 0; j < 4; ++j)
        b[j] = *(const bf16x8*)&Bs[(wn * 64 + j * 16 + l16) * 64 + kk + quad * 8];
#pragma unroll
      for (int i = 0; i < 2; ++i)
#pragma unroll
        for (int j = 0; j < 4; ++j) acc[i][j] = MFMA(a[i], b[j], acc[i][j]);
    }
  }

  // epilogue: C/D layout col=l16, row=quad*4+r (m89-verified)
#pragma unroll
  for (int i = 0; i < 2; ++i) {
#pragma unroll
    for (int j = 0; j < 4; ++j) {
      const int col     = n0 + wn * 64 + j * 16 + l16;
      const int rowbase = m0 + wm * 32 + i * 16 + quad * 4;
      if (EPI == 1) {
        if (col < D_) {
          bf16* qb = (bf16*)Cout;
#pragma unroll
          for (int r = 0; r < 4; ++r)  // fold softmax scale 1/sqrt(64) into q
            qb[(size_t)(rowbase + r) * D_ + col] = (bf16)(acc[i][j][r] * 0.125f);
        } else if (col < D_ + HD_) {
#pragma unroll
          for (int r = 0; r < 4; ++r)
            kb[(size_t)(rowbase + r) * HD_ + (col - D_)] = (bf16)acc[i][j][r];
        } else {
          bf16 o[4] = {(bf16)acc[i][j][0], (bf16)acc[i][j][1],
                       (bf16)acc[i][j][2], (bf16)acc[i][j][3]};
          *(uint2*)&vT[(size_t)(col - D_ - HD_) * M_ + rowbase] = *(const uint2*)o;
        }
      } else {
        float* outp = (float*)Cout;
        const float bvv = (float)bias[col];
#pragma unroll
        for (int r = 0; r < 4; ++r)
          outp[(size_t)(rowbase + r) * D_ + col] = acc[i][j][r] + bvv;
      }
    }
  }
}

// ---------------------------------------------------------------------------
// Windowed attention (MQA), Q-tile = 128, q pre-scaled by 1/sqrt(64).
// QK computed TRANSPOSED (A=K-frag, B=Q-frag -> C/D col=t, row=s): each lane
// then holds 4 consecutive s for fixed t, so the Ps[t][s] store is 8x
// ds_write_b64 instead of 32x ds_write_b16 (r8 softmax was LDS-inst-bound).
// Row-sum l becomes per-t partials reduced over quad (2-step shuffle),
// redistributed once at kernel end via a small LDS array.
// Double-buffered K/V staging via global_load_lds; PV unchanged (Ps rows
// contiguous b128 reads; V pre-transposed vT[h][m]).
// Un-normalized softmax (NaN-free); in-place q/o safe.
// ---------------------------------------------------------------------------
__global__ __launch_bounds__(256) void attn_win128(
    const bf16* __restrict__ q, const bf16* __restrict__ k,
    const bf16* __restrict__ vT, bf16* __restrict__ o) {
  __shared__ __align__(16) bf16 Qs[128 * 64];     // 16 KB
  __shared__ __align__(16) bf16 Ks[2][64 * 64];   // 16 KB
  __shared__ __align__(16) bf16 Vt[2][64 * 64];   // 16 KB [h][s]
  __shared__ __align__(16) bf16 Ps[128 * 72];     // 18 KB padded
  __shared__ float ls[4][32];                     // per-wave l[t] redistribute

  const int tid  = threadIdx.x;
  const int w    = tid >> 6;
  const int lane = tid & 63;
  const int quad = lane >> 4;
  const int l16  = lane & 15;
  const int lrow = lane >> 3;        // 0..7
  const int lcol = (lane & 7) * 8;   // 0..56

  const int t0 = blockIdx.x * 128;
  const int n  = blockIdx.y;
  const int b  = blockIdx.z;

  // stage Q tile (128 rows x 64): 16 insts, 4 per wave
#pragma unroll
  for (int t = 0; t < 4; ++t) {
    const int inst = w * 4 + t;
    gld_lds16(&q[((size_t)(b * T_ + t0 + inst * 8 + lrow)) * D_ + n * HD_ + lcol],
              &Qs[inst * 512]);
  }

  auto stageKV = [&](int st, int pb) {
#pragma unroll
    for (int t = 0; t < 2; ++t) {
      const int inst = w * 2 + t;
      gld_lds16(&k[((size_t)(b * T_ + st + inst * 8 + lrow)) * HD_ + lcol],
                &Ks[pb][inst * 512]);
      gld_lds16(&vT[(size_t)(inst * 8 + lrow) * M_ + b * T_ + st + lcol],
                &Vt[pb][inst * 512]);
    }
  };

  const int st_lo = (t0 - WIN_ > 0) ? t0 - WIN_ : 0;
  const int st_hi = (t0 + WIN_ + 64 < T_ - 64) ? t0 + WIN_ + 64 : T_ - 64;

  stageKV(st_lo, 0);
  int pb = 0;

  f32x4 o_acc[2][4] = {};
  float l_part[2] = {0.0f, 0.0f};  // per-t partials, t = t0 + w*32 + tt*16 + l16

  for (int st = st_lo; st <= st_hi; st += 64) {
    __syncthreads();  // drains vmcnt: buf[pb] (and Qs) ready; prior PV done
    if (st + 64 <= st_hi) stageKV(st + 64, pb ^ 1);  // overlapped prefetch

    // S^T = K Q^T : MFMA(A=K-frag, B=Q-frag) -> C/D col=t, row=s
    f32x4 sacc[4][2] = {};  // [stile][tt]
#pragma unroll
    for (int kk = 0; kk < 64; kk += 32) {
      bf16x8 ak[4], bq[2];
#pragma unroll
      for (int stile = 0; stile < 4; ++stile)
        ak[stile] = *(const bf16x8*)&Ks[pb][(stile * 16 + l16) * 64 + kk + quad * 8];
#pragma unroll
      for (int tt = 0; tt < 2; ++tt)
        bq[tt] = *(const bf16x8*)&Qs[(w * 32 + tt * 16 + l16) * 64 + kk + quad * 8];
#pragma unroll
      for (int stile = 0; stile < 4; ++stile)
#pragma unroll
        for (int tt = 0; tt < 2; ++tt)
          sacc[stile][tt] = MFMA(ak[stile], bq[tt], sacc[stile][tt]);
    }

    // softmax numerators; lane holds col t = w*32+tt*16+l16, rows
    // s = stile*16+quad*4+r -> vectorized b64 stores into Ps[t][s]
    const int off_t = st - t0;
    const bool need_mask =
        (off_t < w * 32 - (WIN_ - 31)) || (off_t > w * 32 + (WIN_ - 63));
    if (!need_mask) {
#pragma unroll
      for (int tt = 0; tt < 2; ++tt) {
#pragma unroll
        for (int stile = 0; stile < 4; ++stile) {
          bf16 pk[4];
          float psum = 0.0f;
#pragma unroll
          for (int r = 0; r < 4; ++r) {
            const float p = __expf(fminf(sacc[stile][tt][r], 30.0f));
            psum += p;
            pk[r] = (bf16)p;
          }
          l_part[tt] += psum;
          *(uint2*)&Ps[(w * 32 + tt * 16 + l16) * 72 + stile * 16 + quad * 4] =
              *(const uint2*)pk;
        }
      }
    } else {
#pragma unroll
      for (int tt = 0; tt < 2; ++tt) {
        const int t = t0 + w * 32 + tt * 16 + l16;
#pragma unroll
        for (int stile = 0; stile < 4; ++stile) {
          bf16 pk[4];
          float psum = 0.0f;
#pragma unroll
          for (int r = 0; r < 4; ++r) {
            const int s = st + stile * 16 + quad * 4 + r;
            const int d = t - s;
            const float p = (d > WIN_ || d < -WIN_)
                                ? 0.0f
                                : __expf(fminf(sacc[stile][tt][r], 30.0f));
            psum += p;
            pk[r] = (bf16)p;
          }
          l_part[tt] += psum;
          *(uint2*)&Ps[(w * 32 + tt * 16 + l16) * 72 + stile * 16 + quad * 4] =
              *(const uint2*)pk;
        }
      }
    }
    __syncthreads();  // Ps visible (prefetch drains here, overlapped)

    // O += P V  (A-frag: Ps rows t contiguous in s; B-frag: Vt rows h)
#pragma unroll
    for (int kk = 0; kk < 64; kk += 32) {
      bf16x8 ap[2];
#pragma unroll
      for (int rg = 0; rg < 2; ++rg)
        ap[rg] = *(const bf16x8*)&Ps[(w * 32 + rg * 16 + l16) * 72 + kk + quad * 8];
#pragma unroll
      for (int nt = 0; nt < 4; ++nt) {
        bf16x8 bv = *(const bf16x8*)&Vt[pb][(nt * 16 + l16) * 64 + kk + quad * 8];
#pragma unroll
        for (int rg = 0; rg < 2; ++rg)
          o_acc[rg][nt] = MFMA(ap[rg], bv, o_acc[rg][nt]);
      }
    }
    pb ^= 1;
  }

  // finalize l[t]: reduce per-t partials across the 4 quads, redistribute
#pragma unroll
  for (int tt = 0; tt < 2; ++tt) {
    l_part[tt] += __shfl_xor(l_part[tt], 16);
    l_part[tt] += __shfl_xor(l_part[tt], 32);
    if (quad == 0) ls[w][tt * 16 + l16] = l_part[tt];
  }
  __syncthreads();

#pragma unroll
  for (int rg = 0; rg < 2; ++rg) {
#pragma unroll
    for (int r = 0; r < 4; ++r) {
      const float lr = ls[w][rg * 16 + quad * 4 + r] + 1e-30f;
      const int t = t0 + w * 32 + rg * 16 + quad * 4 + r;
#pragma unroll
      for (int nt = 0; nt < 4; ++nt) {
        const int h = nt * 16 + l16;
        o[((size_t)(b * T_ + t)) * D_ + n * HD_ + h] =
            (bf16)(o_acc[rg][nt][r] / lr);
      }
    }
  }
}

// ---------------------------------------------------------------------------
extern "C" void kernel_launch(void* const* d_in, const int* in_sizes, int n_in,
                              void* d_out, int out_size, void* d_ws, size_t ws_size,
                              hipStream_t stream) {
  float* out = (float*)d_out;  // reference output dtype is float32

  bf16* xc   = (bf16*)d_ws;                   // 4096 x 1024
  bf16* wqkv = xc   + (size_t)M_ * D_;        // 1152 x 1024
  bf16* wfc  = wqkv + (size_t)NQKV * D_;      // 1024 x 1024
  bf16* bfc  = wfc  + (size_t)D_ * D_;        // 1024
  bf16* qb   = bfc  + D_;                     // 4096 x 1024 (attn out in-place)
  bf16* kb   = qb   + (size_t)M_ * D_;        // 4096 x 64
  bf16* vT   = kb   + (size_t)M_ * HD_;       // 64 x 4096 (transposed)

  dim3 blk(256);
  conv_all<<<dim3((6423552 / 4 + 255) / 256), blk, 0, stream>>>(
      (const float*)d_in[0], (const float*)d_in[1], (const float*)d_in[2],
      (const float*)d_in[3], (const float*)d_in[4], (const float*)d_in[5],
      xc, wqkv, wfc, bfc);

  gemm64x128<1><<<dim3(M_ / 64, NQKV / 128), blk, 0, stream>>>(
      xc, wqkv, (void*)qb, nullptr, kb, vT, NQKV, D_);

  attn_win128<<<dim3(T_ / 128, NH_, B_), blk, 0, stream>>>(qb, kb, vT, qb);

  gemm64x128<2><<<dim3(M_ / 64, D_ / 128), blk, 0, stream>>>(
      qb, wfc, (void*)out, bfc, nullptr, nullptr, D_, D_);
}